// Round 10
// baseline (467.046 us; speedup 1.0000x reference)
//
#include <hip/hip_runtime.h>

#define EPS_BN 1e-5f
#define BINSHIFT 9
#define BINW 512
#define P_EPB 8192   // edges per block in count/scatter passes
#define LDS_CAP 10240
#define NREP 32      // stat-accumulator replicas (atomic de-contention)

typedef __attribute__((ext_vector_type(8))) short short8;
typedef __attribute__((ext_vector_type(4))) float f32x4;

__device__ __forceinline__ unsigned short f2bf(float x) {
    unsigned int u = __float_as_uint(x);
    u += 0x7fffu + ((u >> 16) & 1u);
    return (unsigned short)(u >> 16);
}
__device__ __forceinline__ float bf2f(unsigned short h) {
    return __uint_as_float(((unsigned int)h) << 16);
}
__device__ __forceinline__ float bflo(unsigned u) { return __uint_as_float(u << 16); }
__device__ __forceinline__ float bfhi(unsigned u) { return __uint_as_float(u & 0xffff0000u); }

// inclusive scan over a[0..511], 512 threads (ends synced)
__device__ __forceinline__ void scan512(int* a, int t) {
    for (int off = 1; off < 512; off <<= 1) {
        int v = (t >= off) ? a[t - off] : 0;
        __syncthreads();
        a[t] += v;
        __syncthreads();
    }
}

// ---------------------------------------------------------------- GEMM body
// Y = A[N,128] @ [Wself | Wneigh] (fp32 weights staged+swizzled to bf16 LDS
// fragment order per block). cols [0,MSELF) -> self out (bf16 or fp32);
// cols [MSELF,MT) -> bf16 row-major Ynb. FUSEBN: BN+ReLU on A columns
// (sums NREP-replicated). AFP32: A is fp32 (inline cvt).
template <int MT, int MSELF, bool SELFBF, bool FUSEBN, bool AFP32>
__device__ __forceinline__ void gemm_body(int bid, const unsigned short* __restrict__ Ab,
                                          const float* __restrict__ Af,
                                          const float* __restrict__ Ws,
                                          const float* __restrict__ Wn,
                                          float* __restrict__ YselfF,
                                          unsigned short* __restrict__ YselfB,
                                          unsigned short* __restrict__ Ynb, int N,
                                          const float* __restrict__ sums,
                                          const float* __restrict__ gamma,
                                          const float* __restrict__ beta, float invN) {
    constexpr int K = 128;
    constexpr int NCT = MT / 16;
    constexpr int KS = K / 32;
    constexpr int MNB = MT - MSELF;
    constexpr int CL = (NCT == 16) ? 4 : 3;
    __shared__ unsigned short Bl[KS * NCT * 64 * 8];
    __shared__ float ssc[128], ssh[128];
    int tid = threadIdx.x;

    // stage fp32 weights -> bf16 LDS, fragment order (same math as old cvt_w)
    for (int i = tid; i < KS * NCT * 64 * 8; i += 256) {
        int j = i & 7, L = (i >> 3) & 63, c = (i >> 9) & (NCT - 1), kk = i >> (9 + CL);
        int k = kk * 32 + (L >> 4) * 8 + j;
        int col = c * 16 + (L & 15);
        float v = (col < MSELF) ? Ws[k * MSELF + col] : Wn[k * MNB + (col - MSELF)];
        Bl[i] = f2bf(v);
    }
    if (FUSEBN && tid < 128) {
        int c = tid;
        float su = 0.f, sq = 0.f;
        for (int r = 0; r < NREP; r++) {
            su += sums[r * 256 + c];
            sq += sums[r * 256 + 128 + c];
        }
        float mu = su * invN;
        float var = sq * invN - mu * mu;
        float sc = gamma[c] * rsqrtf(var + EPS_BN);
        ssc[c] = sc;
        ssh[c] = beta[c] - mu * sc;
    }
    __syncthreads();

    int wv = tid >> 6, lane = tid & 63;
    int row0 = bid * 128 + wv * 32;
    int m = lane & 15, quad = lane >> 4;

    short8 afrag[2][KS];
#pragma unroll
    for (int t = 0; t < 2; t++) {
        int arow = row0 + t * 16 + m;
        if (arow >= N) arow = N - 1;
#pragma unroll
        for (int kk = 0; kk < KS; kk++) {
            short8 raw;
            if (AFP32) {
                const float* ap = Af + (size_t)arow * K + quad * 8 + kk * 32;
                f32x4 a = *(const f32x4*)ap;
                f32x4 b = *(const f32x4*)(ap + 4);
#pragma unroll
                for (int j = 0; j < 4; j++) {
                    raw[j] = (short)f2bf(a[j]);
                    raw[4 + j] = (short)f2bf(b[j]);
                }
            } else {
                raw = *(const short8*)(Ab + (size_t)arow * K + quad * 8 + kk * 32);
            }
            if (FUSEBN) {
#pragma unroll
                for (int j = 0; j < 8; j++) {
                    int c = kk * 32 + quad * 8 + j;
                    float f = bf2f((unsigned short)raw[j]) * ssc[c] + ssh[c];
                    raw[j] = (short)f2bf(fmaxf(f, 0.f));
                }
            }
            afrag[t][kk] = raw;
        }
    }

    f32x4 acc[2][NCT];
#pragma unroll
    for (int t = 0; t < 2; t++)
        for (int c = 0; c < NCT; c++)
            for (int j = 0; j < 4; j++) acc[t][c][j] = 0.f;

#pragma unroll
    for (int kk = 0; kk < KS; kk++) {
#pragma unroll
        for (int c = 0; c < NCT; c++) {
            short8 bfrag = *(const short8*)&Bl[((kk * NCT + c) * 64 + lane) * 8];
#pragma unroll
            for (int t = 0; t < 2; t++)
                acc[t][c] = __builtin_amdgcn_mfma_f32_16x16x32_bf16(afrag[t][kk], bfrag,
                                                                    acc[t][c], 0, 0, 0);
        }
    }

    // C/D layout: col = lane&15, row = quad*4 + reg
#pragma unroll
    for (int t = 0; t < 2; t++) {
#pragma unroll
        for (int c = 0; c < NCT; c++) {
            int colg = c * 16 + m;
#pragma unroll
            for (int r = 0; r < 4; r++) {
                int row = row0 + t * 16 + quad * 4 + r;
                if (row < N) {
                    float v = acc[t][c][r];
                    if (colg < MSELF) {
                        if (SELFBF)
                            YselfB[(size_t)row * MSELF + colg] = f2bf(v);
                        else
                            YselfF[(size_t)row * MSELF + colg] = v;
                    } else {
                        Ynb[(size_t)row * MNB + (colg - MSELF)] = f2bf(v);
                    }
                }
            }
        }
    }
}

// ------------------------------------------------ K1: p1 histogram | gemm1
__global__ __launch_bounds__(256) void k1_front(const int* __restrict__ dst,
                                                int* __restrict__ counts, int E, int NB,
                                                int NBLK, const float* __restrict__ X,
                                                const float* __restrict__ Ws1,
                                                const float* __restrict__ Wn1,
                                                unsigned short* __restrict__ bufS,
                                                unsigned short* __restrict__ tab, int N) {
    if ((int)blockIdx.x < NBLK) {
        __shared__ int hist[512];
        int tid = threadIdx.x;
        int blk = blockIdx.x;
        int e0 = blk * P_EPB, e1 = min(e0 + P_EPB, E);
        for (int b = tid; b < 512; b += 256) hist[b] = 0;
        __syncthreads();
        for (int e = e0 + tid; e < e1; e += 256) atomicAdd(&hist[dst[e] >> BINSHIFT], 1);
        __syncthreads();
        for (int b = tid; b < NB; b += 256) counts[blk * NB + b] = hist[b];
    } else {
        gemm_body<256, 128, true, false, true>(blockIdx.x - NBLK, nullptr, X, Ws1, Wn1,
                                               nullptr, bufS, tab, N, nullptr, nullptr,
                                               nullptr, 0.f);
    }
}

// ------------------------------------------------ gemm2 (BN1+ReLU fused A-load)
__global__ __launch_bounds__(256) void gemm2_kernel(const unsigned short* __restrict__ h1b,
                                                    const float* __restrict__ Ws2,
                                                    const float* __restrict__ Wn2,
                                                    float* __restrict__ out,
                                                    unsigned short* __restrict__ tab, int N,
                                                    const float* __restrict__ sums,
                                                    const float* __restrict__ g1,
                                                    const float* __restrict__ be1,
                                                    float invN) {
    gemm_body<128, 64, false, true, false>(blockIdx.x, h1b, nullptr, Ws2, Wn2, out,
                                           nullptr, tab, N, sums, g1, be1, invN);
}

// ------------------------------------------------ p3: LDS-binned scatter (p2a folded)
// Edge record packed to 4B: (src << 9) | (dst & 511).
__global__ __launch_bounds__(512) void p3_scatter(const int* __restrict__ src,
                                                  const int* __restrict__ dst,
                                                  const int* __restrict__ counts,
                                                  unsigned* __restrict__ epack,
                                                  int E, int NB, int NBLK) {
    __shared__ unsigned lp[P_EPB];
    __shared__ int hist[512];
    __shared__ int sBase[513];
    __shared__ int cursor[512];
    __shared__ int bexcl[512];
    __shared__ int myrel[512];
    int t = threadIdx.x;
    int blk = blockIdx.x;
    int e0 = blk * P_EPB, e1 = min(e0 + P_EPB, E), m = e1 - e0;
    // per-bin: column total (cs) and prefix over earlier edge-blocks (ms)
    int cs = 0, ms = 0;
    if (t < NB)
        for (int q = 0; q < NBLK; q++) {
            int v = counts[q * NB + t];
            cs += v;
            if (q < blk) ms += v;
        }
    myrel[t] = ms;
    bexcl[t] = cs;
    __syncthreads();
    scan512(bexcl, t);
    bexcl[t] -= cs;  // exclusive bin base
    hist[t] = 0;
    __syncthreads();
    for (int e = e0 + t; e < e1; e += 512) atomicAdd(&hist[dst[e] >> BINSHIFT], 1);
    __syncthreads();
    int h = hist[t];
    scan512(hist, t);
    int excl = hist[t] - h;
    sBase[t] = excl;
    cursor[t] = excl;
    if (t == 0) sBase[512] = m;
    __syncthreads();
    for (int e = e0 + t; e < e1; e += 512) {
        int d = dst[e];
        int pos = atomicAdd(&cursor[d >> BINSHIFT], 1);
        lp[pos] = ((unsigned)src[e] << BINSHIFT) | ((unsigned)d & (BINW - 1));
    }
    __syncthreads();
    for (int i = t; i < m; i += 512) {
        int lo = 0, hi = NB;
        while (hi - lo > 1) {
            int mid = (lo + hi) >> 1;
            if (sBase[mid] <= i) lo = mid; else hi = mid;
        }
        epack[bexcl[lo] + myrel[lo] + (i - sBase[lo])] = lp[i];
    }
}

// ------------------------------------------------ p4: per-bin CSR finalize (p2a folded)
__global__ __launch_bounds__(512) void p4_csr(const unsigned* __restrict__ epack,
                                              const int* __restrict__ counts,
                                              int* __restrict__ row_start,
                                              int* __restrict__ cntg,
                                              float* __restrict__ inv_deg,
                                              int* __restrict__ csr_src, int N, int NB,
                                              int NBLK) {
    __shared__ int ncnt[512];
    __shared__ int cursor[512];
    __shared__ int bb[512];
    __shared__ int lsrc[LDS_CAP];
    int t = threadIdx.x;
    int b = blockIdx.x;
    int cs = 0;
    if (t < NB)
        for (int q = 0; q < NBLK; q++) cs += counts[q * NB + t];
    bb[t] = cs;
    __syncthreads();
    scan512(bb, t);
    int e1 = bb[b];
    int e0 = (b > 0) ? bb[b - 1] : 0;
    int m = e1 - e0;
    int nbase = b << BINSHIFT;
    int nn = min(N - nbase, BINW);
    ncnt[t] = 0;
    __syncthreads();
    for (int i = e0 + t; i < e1; i += 512) atomicAdd(&ncnt[epack[i] & (BINW - 1)], 1);
    __syncthreads();
    int c = ncnt[t];
    scan512(ncnt, t);
    int excl = ncnt[t] - c;
    if (t < nn) {
        int node = nbase + t;
        row_start[node] = e0 + excl;
        cntg[node] = c;
        inv_deg[node] = 1.0f / fmaxf((float)c, 1.0f);
    }
    cursor[t] = excl;
    __syncthreads();
    for (int i = e0 + t; i < e1; i += 512) {
        unsigned v = epack[i];
        int pos = atomicAdd(&cursor[v & (BINW - 1)], 1);
        if (pos < LDS_CAP) lsrc[pos] = (int)(v >> BINSHIFT);
    }
    __syncthreads();
    int mm = min(m, LDS_CAP);
    for (int i = t; i < mm; i += 512) csr_src[e0 + i] = lsrc[i];
}

// ------------------------------------------------- aggregation + fused BN stats
// Layer 1: one wave per node (persistent); full 256B row/edge; 16-edge unroll
// (4KB in flight/wave). Self bf16 in, h1 bf16 out. Replicated stat atomics.
__global__ __launch_bounds__(256) void agg_row128(const unsigned int* __restrict__ Sb,
                                                  const unsigned int* __restrict__ T,
                                                  const int* __restrict__ row_start,
                                                  const int* __restrict__ cnt,
                                                  const float* __restrict__ inv_deg,
                                                  const int* __restrict__ csr_src,
                                                  const float* __restrict__ bias,
                                                  unsigned int* __restrict__ Out,
                                                  float* __restrict__ sums,
                                                  int N, int totalWaves) {
    int wv = threadIdx.x >> 6, lane = threadIdx.x & 63;
    int c = lane * 2;
    float bs0 = bias[c], bs1 = bias[c + 1];
    float S0 = 0.f, S1 = 0.f, Q0 = 0.f, Q1 = 0.f;
    for (int n = blockIdx.x * 4 + wv; n < N; n += totalWaves) {
        int start = row_start[n];
        int ec = cnt[n];
        float inv = inv_deg[n];
        float a0 = 0.f, a1 = 0.f;
        int e = 0;
        for (; e + 15 < ec; e += 16) {
            int idx[16];
            unsigned uu[16];
#pragma unroll
            for (int q = 0; q < 16; q++) idx[q] = csr_src[start + e + q];
#pragma unroll
            for (int q = 0; q < 16; q++) uu[q] = T[(size_t)idx[q] * 64 + lane];
#pragma unroll
            for (int q = 0; q < 16; q++) {
                a0 += bflo(uu[q]);
                a1 += bfhi(uu[q]);
            }
        }
        for (; e + 3 < ec; e += 4) {
            int idx[4];
            unsigned uu[4];
#pragma unroll
            for (int q = 0; q < 4; q++) idx[q] = csr_src[start + e + q];
#pragma unroll
            for (int q = 0; q < 4; q++) uu[q] = T[(size_t)idx[q] * 64 + lane];
#pragma unroll
            for (int q = 0; q < 4; q++) {
                a0 += bflo(uu[q]);
                a1 += bfhi(uu[q]);
            }
        }
        for (; e < ec; e++) {
            unsigned u0 = T[(size_t)csr_src[start + e] * 64 + lane];
            a0 += bflo(u0);
            a1 += bfhi(u0);
        }
        unsigned su = Sb[(size_t)n * 64 + lane];
        float h0 = bflo(su) + a0 * inv + bs0;
        float h1 = bfhi(su) + a1 * inv + bs1;
        Out[(size_t)n * 64 + lane] = (unsigned)f2bf(h0) | ((unsigned)f2bf(h1) << 16);
        S0 += h0; Q0 += h0 * h0;
        S1 += h1; Q1 += h1 * h1;
    }
    __shared__ float ls[256];
    ls[threadIdx.x] = 0.f;
    __syncthreads();
    atomicAdd(&ls[c], S0);
    atomicAdd(&ls[c + 1], S1);
    atomicAdd(&ls[128 + c], Q0);
    atomicAdd(&ls[129 + c], Q1);
    __syncthreads();
    float* dstS = sums + (size_t)(blockIdx.x & (NREP - 1)) * 256;
    atomicAdd(&dstS[threadIdx.x], ls[threadIdx.x]);
}

// Layer 2: two 32-lane groups per wave (persistent); full 128B row/edge;
// 8-edge unroll. Self fp32 in d_out, in-place. Replicated stats.
__global__ __launch_bounds__(256) void agg_row64(const unsigned int* __restrict__ T,
                                                 const int* __restrict__ row_start,
                                                 const int* __restrict__ cnt,
                                                 const float* __restrict__ inv_deg,
                                                 const int* __restrict__ csr_src,
                                                 const float* __restrict__ bias,
                                                 float* Self, float* __restrict__ sums,
                                                 int N, int totalHalf) {
    int wv = threadIdx.x >> 6, L = threadIdx.x & 63;
    int g = L >> 5, h = L & 31;
    int c = h * 2;
    float bs0 = bias[c], bs1 = bias[c + 1];
    float S0 = 0.f, S1 = 0.f, Q0 = 0.f, Q1 = 0.f;
    for (int n = (blockIdx.x * 4 + wv) * 2 + g; n < N; n += totalHalf) {
        int start = row_start[n];
        int ec = cnt[n];
        float inv = inv_deg[n];
        float a0 = 0.f, a1 = 0.f;
        int e = 0;
        for (; e + 7 < ec; e += 8) {
            int idx[8];
            unsigned uu[8];
#pragma unroll
            for (int q = 0; q < 8; q++) idx[q] = csr_src[start + e + q];
#pragma unroll
            for (int q = 0; q < 8; q++) uu[q] = T[(size_t)idx[q] * 32 + h];
#pragma unroll
            for (int q = 0; q < 8; q++) {
                a0 += bflo(uu[q]);
                a1 += bfhi(uu[q]);
            }
        }
        for (; e < ec; e++) {
            unsigned u0 = T[(size_t)csr_src[start + e] * 32 + h];
            a0 += bflo(u0);
            a1 += bfhi(u0);
        }
        size_t off = (size_t)n * 64 + c;
        float h0 = Self[off] + a0 * inv + bs0;
        float h1 = Self[off + 1] + a1 * inv + bs1;
        Self[off] = h0;
        Self[off + 1] = h1;
        S0 += h0; Q0 += h0 * h0;
        S1 += h1; Q1 += h1 * h1;
    }
    __shared__ float ls[128];
    if (threadIdx.x < 128) ls[threadIdx.x] = 0.f;
    __syncthreads();
    atomicAdd(&ls[c], S0);
    atomicAdd(&ls[c + 1], S1);
    atomicAdd(&ls[64 + c], Q0);
    atomicAdd(&ls[65 + c], Q1);
    __syncthreads();
    if (threadIdx.x < 128) {
        float* dstS = sums + (size_t)(blockIdx.x & (NREP - 1)) * 128;
        atomicAdd(&dstS[threadIdx.x], ls[threadIdx.x]);
    }
}

// layer-2 apply (finalize folded, NREP-replicated sums): fp32 in-place, no ReLU
__global__ __launch_bounds__(256) void bn_apply_f64(float* H, const float* __restrict__ sums,
                                                    const float* __restrict__ gamma,
                                                    const float* __restrict__ beta,
                                                    int N, float invN) {
    __shared__ float ss[128];
    int tid = threadIdx.x;
    if (tid < 64) {
        float su = 0.f, sq = 0.f;
        for (int r = 0; r < NREP; r++) {
            su += sums[r * 128 + tid];
            sq += sums[r * 128 + 64 + tid];
        }
        float mu = su * invN;
        float var = sq * invN - mu * mu;
        float sc = gamma[tid] * rsqrtf(var + EPS_BN);
        ss[tid] = sc;
        ss[64 + tid] = beta[tid] - mu * sc;
    }
    __syncthreads();
    int total4 = N * 16;
    float4* H4 = (float4*)H;
    for (int i = blockIdx.x * 256 + threadIdx.x; i < total4; i += 256 * gridDim.x) {
        int c0 = (i * 4) & 63;
        float4 v = H4[i];
        float4 sc = *(const float4*)&ss[c0];
        float4 sh = *(const float4*)&ss[64 + c0];
        v.x = v.x * sc.x + sh.x;
        v.y = v.y * sc.y + sh.y;
        v.z = v.z * sc.z + sh.z;
        v.w = v.w * sc.w + sh.w;
        H4[i] = v;
    }
}

// ---------------------------------------------------------------- launch
extern "C" void kernel_launch(void* const* d_in, const int* in_sizes, int n_in,
                              void* d_out, int out_size, void* d_ws, size_t ws_size,
                              hipStream_t stream) {
    const float* X = (const float*)d_in[0];
    const int* src = (const int*)d_in[1];
    const int* dst = (const int*)d_in[2];
    const float* Wself1 = (const float*)d_in[3];
    const float* Wneigh1 = (const float*)d_in[4];
    const float* b1 = (const float*)d_in[5];
    const float* g1 = (const float*)d_in[6];
    const float* be1 = (const float*)d_in[7];
    const float* Wself2 = (const float*)d_in[8];
    const float* Wneigh2 = (const float*)d_in[9];
    const float* b2 = (const float*)d_in[10];
    const float* g2 = (const float*)d_in[11];
    const float* be2 = (const float*)d_in[12];
    float* out = (float*)d_out;

    const int N = in_sizes[0] / 128;
    const int E = in_sizes[1];
    const int NB = (N + BINW - 1) >> BINSHIFT;    // 196
    const int NBLK = (E + P_EPB - 1) / P_EPB;     // 196

    char* p = (char*)d_ws;
    auto carve = [&](size_t bytes) {
        char* r = p;
        p += (bytes + 255) & ~(size_t)255;
        return r;
    };
    float* sums1 = (float*)carve((size_t)NREP * 256 * 4);
    float* sums2 = (float*)carve((size_t)NREP * 128 * 4);
    size_t zero_bytes = (size_t)(p - (char*)d_ws);
    int* counts = (int*)carve((size_t)NBLK * NB * 4);
    unsigned* epack = (unsigned*)carve((size_t)E * 4);
    int* csr_src = (int*)carve((size_t)E * 4);
    int* row_start = (int*)carve((size_t)N * 4);
    int* cntg = (int*)carve((size_t)N * 4);
    float* inv_deg = (float*)carve((size_t)N * 4);
    unsigned short* bufS = (unsigned short*)carve((size_t)N * 128 * 2);  // self1 bf16
    unsigned short* tab = (unsigned short*)carve((size_t)N * 128 * 2);   // row-major
    unsigned short* h1b = (unsigned short*)carve((size_t)N * 128 * 2);   // h1 pre-BN bf16

    hipMemsetAsync(d_ws, 0, zero_bytes, stream);

    const float invN = 1.0f / (float)N;
    const int ggrid = (N + 127) / 128;

    // K1: p1 histogram blocks + gemm1 blocks (independent, one dispatch)
    k1_front<<<NBLK + ggrid, 256, 0, stream>>>(dst, counts, E, NB, NBLK, X, Wself1,
                                               Wneigh1, bufS, tab, N);
    p3_scatter<<<NBLK, 512, 0, stream>>>(src, dst, counts, epack, E, NB, NBLK);
    p4_csr<<<NB, 512, 0, stream>>>(epack, counts, row_start, cntg, inv_deg, csr_src, N,
                                   NB, NBLK);
    agg_row128<<<2048, 256, 0, stream>>>(
        (const unsigned int*)bufS, (const unsigned int*)tab, row_start, cntg, inv_deg,
        csr_src, b1, (unsigned int*)h1b, sums1, N, 8192);
    gemm2_kernel<<<ggrid, 256, 0, stream>>>(h1b, Wself2, Wneigh2, out, tab, N, sums1, g1,
                                            be1, invN);
    agg_row64<<<2048, 256, 0, stream>>>(
        (const unsigned int*)tab, row_start, cntg, inv_deg, csr_src, b2, out, sums2,
        N, 16384);
    bn_apply_f64<<<2048, 256, 0, stream>>>(out, sums2, g2, be2, N, invN);
}